// Round 4
// baseline (282.853 us; speedup 1.0000x reference)
//
#include <hip/hip_runtime.h>
#include <hip/hip_bf16.h>
#include <cstdint>

#define D_MODEL 1024
#define HEAD    64
#define SEQ     4096
#define BATCH   4
#define NROWS   (BATCH * SEQ)   // 16384

typedef __attribute__((ext_vector_type(8))) short short8;   // 8 bf16 (MFMA A/B frag)
typedef __attribute__((ext_vector_type(4))) float floatx4;  // MFMA C/D frag

__device__ __forceinline__ ushort f2bf(float f) {
    union { __hip_bfloat16 h; ushort u; } c;
    c.h = __float2bfloat16(f);
    return c.u;
}
__device__ __forceinline__ uint pk2(float a, float b) {
    return (uint)f2bf(a) | ((uint)f2bf(b) << 16);
}

// Async global->LDS, 16B per lane, wave-uniform LDS base (+lane*16 implicit).
__device__ __forceinline__ void gload16(const void* g, void* l) {
    __builtin_amdgcn_global_load_lds(
        (const __attribute__((address_space(1))) unsigned int*)g,
        (__attribute__((address_space(3))) unsigned int*)l, 16, 0, 0);
}

// ---------------------------------------------------------------------------
// wt[which][n][k] = w_which[k][n] bf16, via LDS tile transpose (coalesced both ways).
// Grid (D_MODEL/64, 3), 256 threads.
__global__ __launch_bounds__(256) void wprep_kernel(
    const float* __restrict__ wq, const float* __restrict__ wk,
    const float* __restrict__ wv, ushort* __restrict__ wt)
{
    const int which = blockIdx.y;
    const int k0    = blockIdx.x * 64;
    const float* w  = (which == 0) ? wq : (which == 1) ? wk : wv;
    const int tid   = threadIdx.x;

    __shared__ ushort lds[64][65];

#pragma unroll
    for (int i = 0; i < 16; ++i) {
        int idx = tid + 256 * i;          // 0..4095
        int kl  = idx >> 6;
        int n   = idx & 63;
        lds[n][kl] = f2bf(w[(size_t)(k0 + kl) * 64 + n]);   // coalesced read
    }
    __syncthreads();
#pragma unroll
    for (int i = 0; i < 16; ++i) {
        int idx = tid + 256 * i;
        int n   = idx >> 6;
        int kl  = idx & 63;
        wt[(size_t)(which * 64 + n) * D_MODEL + k0 + kl] = lds[n][kl];  // coalesced write
    }
}

// ---------------------------------------------------------------------------
// proj v4: BARRIER-FREE per-wave streaming GEMM.
// Each wave owns 16 rows x 64 h x full K. Per K-chunk (32 wide):
//   A (16x32 f32, 2KB, 2 DMA) and a PRIVATE copy of W (64x32 bf16, 4KB, 4 DMA)
// staged via global_load_lds into per-wave double-buffered LDS; waits are
// per-wave counted `s_waitcnt vmcnt(6)` -- NO __syncthreads anywhere, so no
// vmcnt(0) drain, waves self-stagger, pipeline stays full (12KB in flight per
// wave, ~144KB/CU >> the ~9KB Little's-law requirement).
// W duplication per wave is L2-hit traffic only (W tile = 128KB, L2-resident).
// LDS swizzle (both-sides): linear DMA dest + pre-swizzled global source +
// swizzled ds_read. Keys: A row128B -> (row&7); W row64B -> ((n>>1)&3).
// Grid (256, 3), 4 waves/block, LDS 48KB -> 3 blocks/CU.
__global__ __launch_bounds__(256) void proj_kernel(
    const float* __restrict__ xq, const float* __restrict__ xk,
    const float* __restrict__ xv, const ushort* __restrict__ wt,
    ushort* __restrict__ qh, ushort* __restrict__ kh, ushort* __restrict__ vt)
{
    const int which = blockIdx.y;
    const float*  x = (which == 0) ? xq : (which == 1) ? xk : xv;
    const ushort* w = wt + (size_t)which * 64 * D_MODEL;

    const int row0 = blockIdx.x * 64;
    const int tid  = threadIdx.x;
    const int wv   = tid >> 6;
    const int ln   = tid & 63;
    const int l16  = ln & 15;
    const int quad = ln >> 4;

    // per-wave private region: A dbuf [2][2048]B then W dbuf [2][4096]B
    __shared__ alignas(16) char lds[4][12288];
    char* Ab = &lds[wv][0];
    char* Wb = &lds[wv][4096];

    // --- pre-swizzled per-lane global sources ---
    // A chunk inst i (i=0,1): local row r = i*8 + (ln>>3), slot = ln&7,
    //   src col floats = (slot ^ (r&7))*4, (r&7) == ln>>3.
    const float* aS[2];
#pragma unroll
    for (int i = 0; i < 2; ++i)
        aS[i] = x + (size_t)(row0 + wv * 16 + i * 8 + (ln >> 3)) * D_MODEL
                  + ((ln & 7) ^ (ln >> 3)) * 4;
    // W chunk inst j (j=0..3): n = j*16 + (ln>>2), slot = ln&3,
    //   src k-slot = slot ^ ((n>>1)&3), ((n>>1)&3) == (ln>>3)&3.
    const ushort* wS[4];
#pragma unroll
    for (int j = 0; j < 4; ++j)
        wS[j] = w + (size_t)(j * 16 + (ln >> 2)) * D_MODEL
                  + (((ln & 3) ^ ((ln >> 3) & 3)) * 8);

    floatx4 acc[4] = {};

#define ISSUE(buf, tt)                                                        \
    do {                                                                      \
        __builtin_amdgcn_sched_barrier(0);                                    \
        gload16(aS[0] + (tt) * 32, Ab + (buf) * 2048 + 0 * 1024);             \
        gload16(aS[1] + (tt) * 32, Ab + (buf) * 2048 + 1 * 1024);             \
        gload16(wS[0] + (tt) * 32, Wb + (buf) * 4096 + 0 * 1024);             \
        gload16(wS[1] + (tt) * 32, Wb + (buf) * 4096 + 1 * 1024);             \
        gload16(wS[2] + (tt) * 32, Wb + (buf) * 4096 + 2 * 1024);             \
        gload16(wS[3] + (tt) * 32, Wb + (buf) * 4096 + 3 * 1024);             \
        __builtin_amdgcn_sched_barrier(0);                                    \
    } while (0)

#define WAITV6                                                                \
    do {                                                                      \
        asm volatile("s_waitcnt vmcnt(6)" ::: "memory");                      \
        __builtin_amdgcn_sched_barrier(0);                                    \
    } while (0)
#define WAITV0                                                                \
    do {                                                                      \
        asm volatile("s_waitcnt vmcnt(0)" ::: "memory");                      \
        __builtin_amdgcn_sched_barrier(0);                                    \
    } while (0)

#define COMPUTE(buf)                                                          \
    do {                                                                      \
        const char* ab_ = Ab + (buf) * 2048;                                  \
        const char* wb_ = Wb + (buf) * 4096;                                  \
        const int ak_ = l16 & 7;                                              \
        float4 f0 = *(const float4*)(ab_ + l16 * 128 + (((quad * 2 + 0) ^ ak_) << 4)); \
        float4 f1 = *(const float4*)(ab_ + l16 * 128 + (((quad * 2 + 1) ^ ak_) << 4)); \
        union { short8 s; uint u[4]; } a_;                                    \
        a_.u[0] = pk2(f0.x, f0.y); a_.u[1] = pk2(f0.z, f0.w);                 \
        a_.u[2] = pk2(f1.x, f1.y); a_.u[3] = pk2(f1.z, f1.w);                 \
        const int wk_ = (l16 >> 1) & 3;                                       \
        _Pragma("unroll")                                                     \
        for (int nt_ = 0; nt_ < 4; ++nt_) {                                   \
            short8 bf_ = *(const short8*)(wb_ + (nt_ * 16 + l16) * 64 + ((quad ^ wk_) << 4)); \
            acc[nt_] = __builtin_amdgcn_mfma_f32_16x16x32_bf16(a_.s, bf_, acc[nt_], 0, 0, 0); \
        }                                                                     \
    } while (0)

    // 32 chunks of K=32. Double-buffered, 2 chunks (12 ops) in flight.
    ISSUE(0, 0);
    ISSUE(1, 1);
    for (int t = 0; t < 30; ++t) {
        WAITV6;                    // chunk t landed (t+1 stays in flight)
        COMPUTE(t & 1);
        ISSUE(t & 1, t + 2);       // refill the buffer just consumed
    }
    WAITV6;  COMPUTE(0);           // t = 30
    WAITV0;  COMPUTE(1);           // t = 31
#undef ISSUE
#undef WAITV6
#undef WAITV0
#undef COMPUTE

    // ---- epilogue: wave wv owns rows row0 + wv*16 .. +15 ----
    const int rbase = row0 + wv * 16 + quad * 4;
    if (which < 2) {
        ushort* y = (which == 0) ? qh : kh;
        const float sc = (which == 0) ? 0.125f : 1.0f;   // fold head^-0.5 into qh
#pragma unroll
        for (int nt = 0; nt < 4; ++nt) {
            int h = nt * 16 + l16;
#pragma unroll
            for (int r = 0; r < 4; ++r)
                y[(size_t)(rbase + r) * HEAD + h] = f2bf(acc[nt][r] * sc);
        }
    } else {
        const int b  = rbase >> 12;
        const int s0 = rbase & (SEQ - 1);
#pragma unroll
        for (int nt = 0; nt < 4; ++nt) {
            int h = nt * 16 + l16;
            uint2 pk = make_uint2(pk2(acc[nt][0], acc[nt][1]), pk2(acc[nt][2], acc[nt][3]));
            *(uint2*)&vt[(size_t)(b * 64 + h) * SEQ + s0] = pk;
        }
    }
}

// ---------------------------------------------------------------------------
// MFMA flash attention, max-free softmax. Block = two PAIRED q-tiles
// (i, 255-i) -> equal work per block (65-66 key-tiles), grid 512, no tail.
// 4 waves K-split each tile (kt ≡ wave mod 4); partial (O,l) additive.
__global__ __launch_bounds__(256, 2) void attn_kernel(
    const ushort* __restrict__ qh, const ushort* __restrict__ kh,
    const ushort* __restrict__ vt, float* __restrict__ out)
{
    const int b    = blockIdx.x >> 7;          // 4 batches x 128 tile-pairs
    const int i    = blockIdx.x & 127;
    const int qsA  = i, qsB = 255 - i;
    const int q0A  = qsA * 16, q0B = qsB * 16;
    const int nA   = (qsA >> 2) + 1;           // key tiles for tile A
    const int nB   = (qsB >> 2) + 1;
    const int tid  = threadIdx.x;
    const int wv   = tid >> 6;
    const int ln   = tid & 63;
    const int l16  = ln & 15;
    const int quad = ln >> 4;

    __shared__ ushort PA[4][16 * 72];
    __shared__ ushort PB[4][16 * 72];
    __shared__ float  Obuf[4][16][68];
    __shared__ float  Lbuf[4][16];

    const ushort* khb = kh + (size_t)b * SEQ * HEAD;
    const ushort* vtb = vt + (size_t)b * HEAD * SEQ;

    // Q B-frags (pre-scaled): n = l16 -> qrow, k = quad*8+j -> h
    const size_t qbA = ((size_t)b * SEQ + q0A + l16) * HEAD + quad * 8;
    const size_t qbB = ((size_t)b * SEQ + q0B + l16) * HEAD + quad * 8;
    const short8 qA0 = *(const short8*)(qh + qbA);
    const short8 qA1 = *(const short8*)(qh + qbA + 32);
    const short8 qB0 = *(const short8*)(qh + qbB);
    const short8 qB1 = *(const short8*)(qh + qbB + 32);

    floatx4 OA[4] = {}, OB[4] = {};
    float rsA = 0.f, rsB = 0.f;
    ushort* myPA = PA[wv];
    ushort* myPB = PB[wv];

    const int cA = (nA > wv) ? (((nA - 1 - wv) >> 2) + 1) : 0;   // steps for A
    const int cB = ((nB - 1 - wv) >> 2) + 1;                     // nB >= 33 > wv
    const int steps = (cA > cB) ? cA : cB;

    for (int s = 0; s < steps; ++s) {
        const int ktA = wv + 4 * s, ktB = wv + 4 * s;
        const bool doA = s < cA, doB = s < cB;
        const int k0A = ktA * 64, k0B = ktB * 64;

        short8 kfA[8], vfA[8], kfB[8], vfB[8];
        if (doA) {
#pragma unroll
            for (int nt = 0; nt < 4; ++nt) {
                const ushort* vp = vtb + (size_t)(nt * 16 + l16) * SEQ + k0A + quad * 8;
                vfA[nt * 2] = *(const short8*)vp; vfA[nt * 2 + 1] = *(const short8*)(vp + 32);
                const ushort* kp = khb + (size_t)(k0A + nt * 16 + l16) * HEAD + quad * 8;
                kfA[nt * 2] = *(const short8*)kp; kfA[nt * 2 + 1] = *(const short8*)(kp + 32);
            }
        }
        if (doB) {
#pragma unroll
            for (int nt = 0; nt < 4; ++nt) {
                const ushort* vp = vtb + (size_t)(nt * 16 + l16) * SEQ + k0B + quad * 8;
                vfB[nt * 2] = *(const short8*)vp; vfB[nt * 2 + 1] = *(const short8*)(vp + 32);
                const ushort* kp = khb + (size_t)(k0B + nt * 16 + l16) * HEAD + quad * 8;
                kfB[nt * 2] = *(const short8*)kp; kfB[nt * 2 + 1] = *(const short8*)(kp + 32);
            }
        }

        // S^T = K Q^T : C row = key (quad*4+r), col = qrow (l16)
        floatx4 aA[4], aB[4];
        if (doA) {
#pragma unroll
            for (int nt = 0; nt < 4; ++nt) {
                floatx4 c = {};
                c = __builtin_amdgcn_mfma_f32_16x16x32_bf16(kfA[nt * 2],     qA0, c, 0, 0, 0);
                c = __builtin_amdgcn_mfma_f32_16x16x32_bf16(kfA[nt * 2 + 1], qA1, c, 0, 0, 0);
                aA[nt] = c;
            }
        }
        if (doB) {
#pragma unroll
            for (int nt = 0; nt < 4; ++nt) {
                floatx4 c = {};
                c = __builtin_amdgcn_mfma_f32_16x16x32_bf16(kfB[nt * 2],     qB0, c, 0, 0, 0);
                c = __builtin_amdgcn_mfma_f32_16x16x32_bf16(kfB[nt * 2 + 1], qB1, c, 0, 0, 0);
                aB[nt] = c;
            }
        }

        if (doA) {
            const bool masked = (ktA == nA - 1);
#pragma unroll
            for (int nt = 0; nt < 4; ++nt) {
                union { ushort u[4]; uint2 w; } pk;
#pragma unroll
                for (int r = 0; r < 4; ++r) {
                    float sv = aA[nt][r];
                    if (masked && (k0A + nt * 16 + quad * 4 + r > q0A + l16)) sv = -3.0e38f;
                    float p = __expf(sv);
                    rsA += p;
                    pk.u[r] = f2bf(p);
                }
                *(uint2*)&myPA[l16 * 72 + nt * 16 + quad * 4] = pk.w;
            }
        }
        if (doB) {
            const bool masked = (ktB == nB - 1);
#pragma unroll
            for (int nt = 0; nt < 4; ++nt) {
                union { ushort u[4]; uint2 w; } pk;
#pragma unroll
                for (int r = 0; r < 4; ++r) {
                    float sv = aB[nt][r];
                    if (masked && (k0B + nt * 16 + quad * 4 + r > q0B + l16)) sv = -3.0e38f;
                    float p = __expf(sv);
                    rsB += p;
                    pk.u[r] = f2bf(p);
                }
                *(uint2*)&myPB[l16 * 72 + nt * 16 + quad * 4] = pk.w;
            }
        }

        if (doA) {
            short8 p0 = *(const short8*)&myPA[l16 * 72 + quad * 8];
            short8 p1 = *(const short8*)&myPA[l16 * 72 + 32 + quad * 8];
#pragma unroll
            for (int nt = 0; nt < 4; ++nt) {
                OA[nt] = __builtin_amdgcn_mfma_f32_16x16x32_bf16(p0, vfA[nt * 2],     OA[nt], 0, 0, 0);
                OA[nt] = __builtin_amdgcn_mfma_f32_16x16x32_bf16(p1, vfA[nt * 2 + 1], OA[nt], 0, 0, 0);
            }
        }
        if (doB) {
            short8 p0 = *(const short8*)&myPB[l16 * 72 + quad * 8];
            short8 p1 = *(const short8*)&myPB[l16 * 72 + 32 + quad * 8];
#pragma unroll
            for (int nt = 0; nt < 4; ++nt) {
                OB[nt] = __builtin_amdgcn_mfma_f32_16x16x32_bf16(p0, vfB[nt * 2],     OB[nt], 0, 0, 0);
                OB[nt] = __builtin_amdgcn_mfma_f32_16x16x32_bf16(p1, vfB[nt * 2 + 1], OB[nt], 0, 0, 0);
            }
        }
    }

    // ---- merge tile A ----
    rsA += __shfl_xor(rsA, 16); rsA += __shfl_xor(rsA, 32);
    if (quad == 0) Lbuf[wv][l16] = rsA;
#pragma unroll
    for (int nt = 0; nt < 4; ++nt)
#pragma unroll
        for (int r = 0; r < 4; ++r)
            Obuf[wv][quad * 4 + r][nt * 16 + l16] = OA[nt][r];
    __syncthreads();
    {
        const int row = tid >> 4, h0 = (tid & 15) * 4;
        float l = Lbuf[0][row] + Lbuf[1][row] + Lbuf[2][row] + Lbuf[3][row];
        float inv = 1.f / l;
        float4 o;
        o.x = (Obuf[0][row][h0+0] + Obuf[1][row][h0+0] + Obuf[2][row][h0+0] + Obuf[3][row][h0+0]) * inv;
        o.y = (Obuf[0][row][h0+1] + Obuf[1][row][h0+1] + Obuf[2][row][h0+1] + Obuf[3][row][h0+1]) * inv;
        o.z = (Obuf[0][row][h0+2] + Obuf[1][row][h0+2] + Obuf[2][row][h0+2] + Obuf[3][row][h0+2]) * inv;
        o.w = (Obuf[0][row][h0+3] + Obuf[1][row][h0+3] + Obuf[2][row][h0+3] + Obuf[3][row][h0+3]) * inv;
        *(float4*)&out[((size_t)b * SEQ + q0A + row) * HEAD + h0] = o;
    }
    __syncthreads();

    // ---- merge tile B ----
    rsB += __shfl_xor(rsB, 16); rsB += __shfl_xor(rsB, 32);
    if (quad == 0) Lbuf[wv][l16] = rsB;
#pragma unroll
    for (int nt = 0; nt < 4; ++nt)
#pragma unroll
        for (int r = 0; r < 4; ++r)
            Obuf[wv][quad * 4 + r][nt * 16 + l16] = OB[nt][r];
    __syncthreads();
    {
        const int row = tid >> 4, h0 = (tid & 15) * 4;
        float l = Lbuf[0][row] + Lbuf[1][row] + Lbuf[2][row] + Lbuf[3][row];
        float inv = 1.f / l;
        float4 o;
        o.x = (Obuf[0][row][h0+0] + Obuf[1][row][h0+0] + Obuf[2][row][h0+0] + Obuf[3][row][h0+0]) * inv;
        o.y = (Obuf[0][row][h0+1] + Obuf[1][row][h0+1] + Obuf[2][row][h0+1] + Obuf[3][row][h0+1]) * inv;
        o.z = (Obuf[0][row][h0+2] + Obuf[1][row][h0+2] + Obuf[2][row][h0+2] + Obuf[3][row][h0+2]) * inv;
        o.w = (Obuf[0][row][h0+3] + Obuf[1][row][h0+3] + Obuf[2][row][h0+3] + Obuf[3][row][h0+3]) * inv;
        *(float4*)&out[((size_t)b * SEQ + q0B + row) * HEAD + h0] = o;
    }
}

// ---------------------------------------------------------------------------
extern "C" void kernel_launch(void* const* d_in, const int* in_sizes, int n_in,
                              void* d_out, int out_size, void* d_ws, size_t ws_size,
                              hipStream_t stream) {
    const float* q  = (const float*)d_in[0];
    const float* k  = (const float*)d_in[1];
    const float* v  = (const float*)d_in[2];
    const float* wq = (const float*)d_in[3];
    const float* wk = (const float*)d_in[4];
    const float* wv = (const float*)d_in[5];

    // ws: qh bf16 (2MB) | kh bf16 (2MB) | vt bf16 [4][64][4096] (2MB) | wt (384KB)
    ushort* qh = (ushort*)d_ws;
    ushort* kh = qh + (size_t)NROWS * HEAD;
    ushort* vt = kh + (size_t)NROWS * HEAD;
    ushort* wt = vt + (size_t)NROWS * HEAD;

    dim3 wgrid(D_MODEL / 64, 3);
    wprep_kernel<<<wgrid, 256, 0, stream>>>(wq, wk, wv, wt);

    dim3 pgrid(NROWS / 64, 3);   // 256 x 3, 4-wave blocks, barrier-free streaming
    proj_kernel<<<pgrid, 256, 0, stream>>>(q, k, v, wt, qh, kh, vt);

    attn_kernel<<<BATCH * 128, 256, 0, stream>>>(qh, kh, vt, (float*)d_out);
}